// Round 1
// baseline (83.490 us; speedup 1.0000x reference)
//
#include <hip/hip_runtime.h>

// Problem constants (from reference)
#define B_    64
#define T_    256
#define VG_   1232
#define S_    32
#define LW_   64
#define VW_   8000
#define NTAGS 8
#define NEG_  (-1e30f)
#define LP_STRIDE 34   // per (b,t): [0]=blank lp, [1..32]=gloss lp, [33]=pad

// ---------------------------------------------------------------------------
// K0: per-tag counts -> reciprocal (tiny, one block)
// ---------------------------------------------------------------------------
__global__ void k_counts(const int* __restrict__ tag_ids, float* __restrict__ invcnt) {
    __shared__ int c[NTAGS];
    if (threadIdx.x < NTAGS) c[threadIdx.x] = 0;
    __syncthreads();
    for (int v = threadIdx.x; v < VG_; v += blockDim.x)
        atomicAdd(&c[tag_ids[v]], 1);   // integer atomics: deterministic
    __syncthreads();
    if (threadIdx.x < NTAGS) invcnt[threadIdx.x] = 1.0f / (float)c[threadIdx.x];
}

// ---------------------------------------------------------------------------
// K1: booster + row logsumexp + gather lp at {blank, glosses[b,:]}.
// One wave per (b,t) row; 4 waves / block. Row = 1232 f32 = 308 float4,
// 5 float4 per lane (last iter partially active: 308-256=52 lanes).
// ---------------------------------------------------------------------------
__global__ __launch_bounds__(256) void k_booster_lse(
    const float* __restrict__ scores, const int* __restrict__ tag_ids,
    const int* __restrict__ glosses, const float* __restrict__ invcnt,
    float* __restrict__ lp_ws)
{
    __shared__ __align__(16) int tagL[VG_];
    __shared__ float tmL[4][NTAGS];
    for (int i = threadIdx.x; i < VG_; i += 256) tagL[i] = tag_ids[i];
    __syncthreads();

    const int lane = threadIdx.x & 63;
    const int wv   = threadIdx.x >> 6;
    const int row  = blockIdx.x * 4 + wv;      // [0, B*T)
    const int b    = row >> 8;                 // row / T_
    const float* srow = scores + (size_t)row * VG_;

    float4 sv[5];
    int4   tv[5];
#pragma unroll
    for (int i = 0; i < 5; ++i) {
        const int idx = i * 64 + lane;
        const bool act = (i < 4) || (lane < 52);
        if (act) {
            sv[i] = ((const float4*)srow)[idx];
            tv[i] = ((const int4*)tagL)[idx];
        } else {
            sv[i] = make_float4(0.f, 0.f, 0.f, 0.f);
            tv[i] = make_int4(0, 0, 0, 0);
        }
    }

    // Pass 1: per-tag sums (inactive elements contribute 0 to tag 0 -> harmless)
    float sums[NTAGS];
#pragma unroll
    for (int n = 0; n < NTAGS; ++n) sums[n] = 0.f;
#pragma unroll
    for (int i = 0; i < 5; ++i) {
        const float xs[4] = {sv[i].x, sv[i].y, sv[i].z, sv[i].w};
        const int   ts[4] = {tv[i].x, tv[i].y, tv[i].z, tv[i].w};
#pragma unroll
        for (int j = 0; j < 4; ++j) {
#pragma unroll
            for (int n = 0; n < NTAGS; ++n)
                sums[n] += (ts[j] == n) ? xs[j] : 0.f;
        }
    }
#pragma unroll
    for (int off = 32; off >= 1; off >>= 1) {
#pragma unroll
        for (int n = 0; n < NTAGS; ++n)
            sums[n] += __shfl_xor(sums[n], off, 64);
    }
    if (lane == 0) {
#pragma unroll
        for (int n = 0; n < NTAGS; ++n)
            tmL[wv][n] = 0.1f * sums[n] * invcnt[n];   // TAG_FACTOR * tag_mean
    }
    __syncthreads();   // uniform across the block

    // Pass 2: boosted = s + tm[tag]; row max + sumexp -> lse
    float m = NEG_;
    float bo[20];
#pragma unroll
    for (int i = 0; i < 5; ++i) {
        const float xs[4] = {sv[i].x, sv[i].y, sv[i].z, sv[i].w};
        const int   ts[4] = {tv[i].x, tv[i].y, tv[i].z, tv[i].w};
        const bool act = (i < 4) || (lane < 52);
#pragma unroll
        for (int j = 0; j < 4; ++j) {
            const float v = act ? (xs[j] + tmL[wv][ts[j]]) : NEG_;
            bo[i * 4 + j] = v;
            m = fmaxf(m, v);
        }
    }
#pragma unroll
    for (int off = 32; off >= 1; off >>= 1)
        m = fmaxf(m, __shfl_xor(m, off, 64));
    float se = 0.f;
#pragma unroll
    for (int k = 0; k < 20; ++k) se += __expf(bo[k] - m);
#pragma unroll
    for (int off = 32; off >= 1; off >>= 1)
        se += __shfl_xor(se, off, 64);
    const float lse = m + __logf(se);

    // Gather: lane 0 -> blank, lanes 1..32 -> glosses[b, lane-1]
    if (lane < 33) {
        const int pos = (lane == 0) ? 0 : glosses[b * S_ + lane - 1];
        const float v = srow[pos] + tmL[wv][tagL[pos]] - lse;
        lp_ws[(size_t)row * LP_STRIDE + lane] = v;
    }
}

// ---------------------------------------------------------------------------
// K2: blocks 0..63 = CTC alpha scan (one wave per batch, state l = lane l,
//     state 64 replicated in a register). Block 64 = NLL gather.
// ---------------------------------------------------------------------------
__global__ __launch_bounds__(256) void k_ctc_nll(
    const float* __restrict__ lp_ws, const int* __restrict__ glosses,
    const int* __restrict__ frames_len, const int* __restrict__ glosses_len,
    const int* __restrict__ words, const float* __restrict__ words_out,
    float* __restrict__ loss_ws, float* __restrict__ nll_ws)
{
    if (blockIdx.x < B_) {
        if (threadIdx.x >= 64) return;       // one wave per batch; no syncthreads below
        const int b = blockIdx.x;
        const int lane = threadIdx.x;

        // ext[l]: even -> blank, odd -> glosses[b, l>>1]
        const bool odd = (lane & 1) != 0;
        const int sIdx = (lane - 1) >> 1;    // valid when odd
        bool skip = false;
        if (odd) {
            const int g = glosses[b * S_ + sIdx];
            skip = (sIdx == 0) || (g != glosses[b * S_ + sIdx - 1]);
        }
        const int off = odd ? (1 + sIdx) : 0;   // index into 34-wide lp row

        const float* lp0 = lp_ws + (size_t)b * T_ * LP_STRIDE;
        float alpha = NEG_;
        float a64   = NEG_;                  // state 64 (blank), replicated on all lanes
        {
            const float lp = lp0[off];
            if (lane <= 1) alpha = lp;       // alpha0[0], alpha0[1]
        }
        const int Tlen = frames_len[b];

        // 1-deep prefetch of the next step's lp to hide L2/L3 latency
        float lp_c  = lp0[LP_STRIDE + off];
        float lpb_c = lp0[LP_STRIDE];
        for (int t = 1; t < T_; ++t) {
            float lp_n = 0.f, lpb_n = 0.f;
            if (t + 1 < T_) {
                const float* lpr = lp0 + (size_t)(t + 1) * LP_STRIDE;
                lp_n  = lpr[off];
                lpb_n = lpr[0];
            }
            float a1  = __shfl_up(alpha, 1, 64);
            float a2  = __shfl_up(alpha, 2, 64);
            const float a63 = __shfl(alpha, 63, 64);
            if (lane == 0) a1 = NEG_;
            if (lane < 2 || !skip) a2 = NEG_;
            const float mm = fmaxf(alpha, fmaxf(a1, a2));
            const float nw = mm + __logf(__expf(alpha - mm) + __expf(a1 - mm) + __expf(a2 - mm)) + lp_c;
            const float m2 = fmaxf(a64, a63);
            const float n64 = m2 + __logf(__expf(a64 - m2) + __expf(a63 - m2)) + lpb_c;
            if (t < Tlen) { alpha = nw; a64 = n64; }   // uniform branch
            lp_c = lp_n; lpb_c = lpb_n;
        }

        const int i1 = 2 * glosses_len[b];            // in [2, 64]
        const int i0 = (i1 - 1 > 0) ? (i1 - 1) : 0;
        const float A0 = __shfl(alpha, i0, 64);
        const float A1 = (i1 >= 64) ? a64 : __shfl(alpha, i1, 64);
        const float mm = fmaxf(A0, A1);
        float loss = -(mm + __logf(__expf(A0 - mm) + __expf(A1 - mm)));
        if (loss > 1e29f) loss = 0.f;
        if (lane == 0) loss_ws[b] = loss;
    } else {
        // NLL: gather B*(LW-1) elements, fixed-order tree reduce
        __shared__ float red[256];
        float acc = 0.f;
        for (int idx = threadIdx.x; idx < B_ * (LW_ - 1); idx += 256) {
            const int b = idx / (LW_ - 1);
            const int t = idx - b * (LW_ - 1);
            const int tgt = words[b * LW_ + t + 1];
            if (tgt != 0)
                acc -= words_out[((size_t)b * LW_ + t) * VW_ + tgt];
        }
        red[threadIdx.x] = acc;
        __syncthreads();
        for (int s = 128; s > 0; s >>= 1) {
            if (threadIdx.x < s) red[threadIdx.x] += red[threadIdx.x + s];
            __syncthreads();
        }
        if (threadIdx.x == 0) nll_ws[0] = red[0];
    }
}

// ---------------------------------------------------------------------------
// K3: final reduce (64 batch losses) + assemble (total, rec, trans)
// ---------------------------------------------------------------------------
__global__ void k_final(const float* __restrict__ loss_ws, const float* __restrict__ nll_ws,
                        float* __restrict__ out) {
    float v = loss_ws[threadIdx.x];
#pragma unroll
    for (int off = 32; off >= 1; off >>= 1) v += __shfl_xor(v, off, 64);
    if (threadIdx.x == 0) {
        const float rec = v;
        const float trans = nll_ws[0];
        out[0] = rec + trans;   // GLOSS_W = WORD_W = 1
        out[1] = rec;
        out[2] = trans;
    }
}

// ---------------------------------------------------------------------------
extern "C" void kernel_launch(void* const* d_in, const int* in_sizes, int n_in,
                              void* d_out, int out_size, void* d_ws, size_t ws_size,
                              hipStream_t stream) {
    const int*   glosses     = (const int*)d_in[0];
    const int*   words       = (const int*)d_in[1];
    const float* scores      = (const float*)d_in[2];
    const float* words_out   = (const float*)d_in[3];
    const int*   frames_len  = (const int*)d_in[4];
    const int*   glosses_len = (const int*)d_in[5];
    const int*   tag_ids     = (const int*)d_in[6];
    float* out = (float*)d_out;

    float* w       = (float*)d_ws;
    float* invcnt  = w;          // 8
    float* loss_ws = w + 8;      // 64
    float* nll_ws  = w + 72;     // 1
    float* lp_ws   = w + 128;    // B*T*34 floats = 2.23 MB

    k_counts<<<1, 256, 0, stream>>>(tag_ids, invcnt);
    k_booster_lse<<<(B_ * T_) / 4, 256, 0, stream>>>(scores, tag_ids, glosses, invcnt, lp_ws);
    k_ctc_nll<<<B_ + 1, 256, 0, stream>>>(lp_ws, glosses, frames_len, glosses_len,
                                          words, words_out, loss_ws, nll_ws);
    k_final<<<1, 64, 0, stream>>>(loss_ws, nll_ws, out);
}